// Round 3
// baseline (5205.590 us; speedup 1.0000x reference)
//
#include <hip/hip_runtime.h>

// Frobenius_71975061946522 — persistent-in-VGPR, hand-rolled grid barrier.
// X (4096x4096 fp32, 64 MB) lives in VGPRs for all 20 iterations:
// 256 blocks x 1024 threads (1 block/CU), thread t of block b holds
// X[16b+r][4t..4t+3] for r=0..15 -> 16 float4 = 64 VGPRs of data.
// Row sums are block-local. Cross-block: colpart (4 MB) -> 64 reducer blocks
// -> col_out (16 KB) + grand total, two grid barriers per iteration.
//
// R2 lesson: cg::grid_group.sync() is a function CALL -> x[] spilled to
// scratch (VGPR_Count=64, 15 GB scratch traffic). This version inlines a
// two-level atomic barrier (16 padded leaf counters -> root, monotonic
// generation counts, s_sleep spin) so x[] stays in registers. Cooperative
// launch is kept only for the co-residency guarantee.

#define NN    4096
#define NV4   1024          // NN/4 float4 per row
#define RPB   16            // rows per block
#define NBLK  256
#define ITERS 20
#define INV_N (1.0f / 4096.0f)

__device__ __forceinline__ float wave_reduce_sum(float v) {
    #pragma unroll
    for (int m = 1; m < 64; m <<= 1) v += __shfl_xor(v, m, 64);
    return v;
}

// Two-level grid barrier, generation `gen` (1-based, monotonic counters).
// Leaf i serves blocks with (b&15)==i; 16 arrivals/gen/leaf; last arriver
// bumps root; everyone spins until root >= 16*gen. Counters zeroed by
// hipMemsetAsync before launch.
__device__ __forceinline__ void grid_barrier(unsigned* bar, int b, unsigned gen) {
    __threadfence();          // release: flush this block's stores
    __syncthreads();
    if (threadIdx.x == 0) {
        unsigned* leaf = bar + (b & 15) * 32;   // 128 B apart
        unsigned* root = bar + 16 * 32;
        unsigned old = __hip_atomic_fetch_add(leaf, 1u, __ATOMIC_RELAXED,
                                              __HIP_MEMORY_SCOPE_AGENT);
        if (old == 16u * gen - 1u)
            __hip_atomic_fetch_add(root, 1u, __ATOMIC_RELAXED,
                                   __HIP_MEMORY_SCOPE_AGENT);
        while (__hip_atomic_load(root, __ATOMIC_RELAXED,
                                 __HIP_MEMORY_SCOPE_AGENT) < 16u * gen)
            __builtin_amdgcn_s_sleep(1);
    }
    __syncthreads();
    __threadfence();          // acquire: invalidate caches before remote reads
}

__global__ __launch_bounds__(1024, 4)
void persist2(const float* __restrict__ X0, float* __restrict__ Xout,
              float* __restrict__ colpart, float* __restrict__ col_out,
              float* __restrict__ blocktot, float* __restrict__ s_glob,
              unsigned* __restrict__ bar)
{
    const int t    = threadIdx.x;
    const int wave = t >> 6;
    const int lane = t & 63;
    const int b    = blockIdx.x;
    const int row0 = b * RPB;

    __shared__ float part[1024 * 17];   // row-partial transpose (68 KB, pad 17)
    __shared__ float rowsum[RPB];
    __shared__ float csum[16][64];      // reducer stage
    __shared__ float ws4[4];

    // Load this thread's 16 float4 of X.
    float4 x[RPB];
    const float4* x0 = (const float4*)X0;
    #pragma unroll
    for (int r = 0; r < RPB; ++r)
        x[r] = x0[(size_t)(row0 + r) * NV4 + t];

    unsigned gen = 0;

    for (int iter = 0; iter < ITERS; ++iter) {
        // ---- phase 1: col partials (registers) + row partials (LDS transpose)
        float4 cacc = make_float4(0.f, 0.f, 0.f, 0.f);
        #pragma unroll
        for (int r = 0; r < RPB; ++r) {
            cacc.x += x[r].x; cacc.y += x[r].y;
            cacc.z += x[r].z; cacc.w += x[r].w;
            part[t * 17 + r] = (x[r].x + x[r].y) + (x[r].z + x[r].w);
        }
        ((float4*)colpart)[(size_t)b * NV4 + t] = cacc;
        __syncthreads();
        // wave w reduces row w: 16 strided reads (<=2-way bank alias) + butterfly
        {
            float v = 0.f;
            #pragma unroll
            for (int k = 0; k < 16; ++k)
                v += part[(lane + 64 * k) * 17 + wave];
            v = wave_reduce_sum(v);
            if (lane == 0) rowsum[wave] = v;
        }
        __syncthreads();
        if (t == 0) {
            float bt = 0.f;
            #pragma unroll
            for (int r = 0; r < RPB; ++r) bt += rowsum[r];
            blocktot[b] = bt;
        }
        grid_barrier(bar, b, ++gen);

        // ---- phase 2: cross-block reductions (blocks 0..64)
        if (b < 64) {
            const int jl = t & 63;
            const int c  = t >> 6;
            const int j  = b * 64 + jl;
            float p = 0.f;
            #pragma unroll
            for (int k = 0; k < 16; ++k)
                p += colpart[(size_t)(c * 16 + k) * NN + j];
            csum[c][jl] = p;
            __syncthreads();
            if (t < 64) {
                float s = 0.f;
                #pragma unroll
                for (int c2 = 0; c2 < 16; ++c2) s += csum[c2][t];
                col_out[b * 64 + t] = s;
            }
        } else if (b == 64) {
            float v = 0.f;
            if (t < 256) v = blocktot[t];
            if (t < 256) {
                v = wave_reduce_sum(v);
                if (lane == 0) ws4[wave] = v;
            }
            __syncthreads();
            if (t == 0) *s_glob = (ws4[0] + ws4[1]) + (ws4[2] + ws4[3]);
        }
        grid_barrier(bar, b, ++gen);

        // ---- phase 3: in-register update X <- relu(P1(X))
        const float s  = *s_glob;
        const float c0 = INV_N + s * (INV_N * INV_N);
        const float4 cv = ((const float4*)col_out)[t];
        float4 csub;
        csub.x = cv.x * INV_N; csub.y = cv.y * INV_N;
        csub.z = cv.z * INV_N; csub.w = cv.w * INV_N;
        #pragma unroll
        for (int r = 0; r < RPB; ++r) {
            const float a = c0 - rowsum[r] * INV_N;
            x[r].x = fmaxf(x[r].x + a - csub.x, 0.f);
            x[r].y = fmaxf(x[r].y + a - csub.y, 0.f);
            x[r].z = fmaxf(x[r].z + a - csub.z, 0.f);
            x[r].w = fmaxf(x[r].w + a - csub.w, 0.f);
        }
    }

    // Final store.
    float4* xo = (float4*)Xout;
    #pragma unroll
    for (int r = 0; r < RPB; ++r)
        xo[(size_t)(row0 + r) * NV4 + t] = x[r];
}

extern "C" void kernel_launch(void* const* d_in, const int* in_sizes, int n_in,
                              void* d_out, int out_size, void* d_ws, size_t ws_size,
                              hipStream_t stream)
{
    const float* X0 = (const float*)d_in[0];
    float* X  = (float*)d_out;

    // ws layout: bar (4 KB of uints) | colpart[256*4096] | col_out[4096] |
    //            blocktot[256] | s_glob[1]
    unsigned* bar    = (unsigned*)d_ws;
    float* colpart   = (float*)d_ws + 1024;
    float* col_out   = colpart + (size_t)NBLK * NN;
    float* blocktot  = col_out + NN;
    float* s_glob    = blocktot + NBLK;

    hipMemsetAsync(d_ws, 0, 4096, stream);   // zero barrier counters

    void* args[] = { (void*)&X0, (void*)&X, (void*)&colpart, (void*)&col_out,
                     (void*)&blocktot, (void*)&s_glob, (void*)&bar };
    hipLaunchCooperativeKernel((const void*)persist2,
                               dim3(NBLK), dim3(1024), args, 0, stream);
}

// Round 4
// 1184.249 us; speedup vs baseline: 4.3957x; 4.3957x over previous
//
#include <hip/hip_runtime.h>

// Frobenius_71975061946522 — persistent-in-VGPR, fence-free sync (R4).
// X (4096x4096 fp32, 64 MB) lives in the unified VGPR/AGPR file across all
// 20 iterations: 256 blocks x 1024 threads (1 block/CU); thread t of block b
// holds X[16b+r][4t..4t+3], r=0..15.
//
// R3 lesson: __threadfence() at agent scope = L2 writeback/invalidate per
// call on multi-XCD -> ~127 us per barrier. This version has ZERO fences:
// all cross-block data moves through memory-side agent-scope atomics
// (global_atomic_add_f32 / relaxed atomic loads), which are coherent at the
// MALL without cache maintenance. One relaxed barrier per iteration.
//
// Cross-block data per iter: colbuf[iter][4096] accumulated via fp32 atomic
// adds (fan-in 256/address, pre-zeroed buffers -> no zeroing races); grand
// total recomputed per-block from the column sums (redundant, ~free).

#define NN    4096
#define NV4   1024
#define RPB   16
#define NBLK  256
#define ITERS 20
#define INV_N (1.0f / 4096.0f)

__device__ __forceinline__ float wave_reduce_sum(float v) {
    #pragma unroll
    for (int m = 1; m < 64; m <<= 1) v += __shfl_xor(v, m, 64);
    return v;
}

__global__ __launch_bounds__(1024, 4)
void persist3(const float* __restrict__ X0, float* __restrict__ Xout,
              float* __restrict__ colbuf,      // [ITERS][NN], pre-zeroed
              unsigned* __restrict__ arrive)   // monotonic barrier counter
{
    const int t    = threadIdx.x;
    const int wave = t >> 6;
    const int lane = t & 63;
    const int b    = blockIdx.x;
    const int row0 = b * RPB;

    __shared__ float part[1024 * 17];   // row-partial transpose (pad 17: <=2-way)
    __shared__ float rowsum[RPB];
    __shared__ float sred[16];

    // Load this thread's 16 float4 of X into registers (AGPR-backed).
    float4 x[RPB];
    const float4* x0 = (const float4*)X0;
    #pragma unroll
    for (int r = 0; r < RPB; ++r)
        x[r] = x0[(size_t)(row0 + r) * NV4 + t];

    for (int iter = 0; iter < ITERS; ++iter) {
        float* cb = colbuf + (size_t)iter * NN;

        // ---- phase 1: row partials -> LDS; column partials -> global atomics
        float4 cacc = make_float4(0.f, 0.f, 0.f, 0.f);
        #pragma unroll
        for (int r = 0; r < RPB; ++r) {
            cacc.x += x[r].x; cacc.y += x[r].y;
            cacc.z += x[r].z; cacc.w += x[r].w;
            part[t * 17 + r] = (x[r].x + x[r].y) + (x[r].z + x[r].w);
        }
        // memory-side fp32 atomic adds (relaxed, agent scope -> no fences)
        __hip_atomic_fetch_add(cb + 4 * t + 0, cacc.x, __ATOMIC_RELAXED, __HIP_MEMORY_SCOPE_AGENT);
        __hip_atomic_fetch_add(cb + 4 * t + 1, cacc.y, __ATOMIC_RELAXED, __HIP_MEMORY_SCOPE_AGENT);
        __hip_atomic_fetch_add(cb + 4 * t + 2, cacc.z, __ATOMIC_RELAXED, __HIP_MEMORY_SCOPE_AGENT);
        __hip_atomic_fetch_add(cb + 4 * t + 3, cacc.w, __ATOMIC_RELAXED, __HIP_MEMORY_SCOPE_AGENT);

        __syncthreads();
        // wave w reduces row w of this block's band
        {
            float v = 0.f;
            #pragma unroll
            for (int k = 0; k < 16; ++k)
                v += part[(lane + 64 * k) * 17 + wave];
            v = wave_reduce_sum(v);
            if (lane == 0) rowsum[wave] = v;
        }

        // ---- barrier (fence-free): drain own vmem, then relaxed arrive/spin
        asm volatile("s_waitcnt vmcnt(0)" ::: "memory");
        __syncthreads();   // all threads drained + rowsum visible
        if (t == 0) {
            __hip_atomic_fetch_add(arrive, 1u, __ATOMIC_RELAXED, __HIP_MEMORY_SCOPE_AGENT);
            const unsigned target = (unsigned)NBLK * (unsigned)(iter + 1);
            while (__hip_atomic_load(arrive, __ATOMIC_RELAXED, __HIP_MEMORY_SCOPE_AGENT) < target)
                __builtin_amdgcn_s_sleep(4);
        }
        __syncthreads();

        // ---- phase 2: read column sums (coherent b64 atomic loads), total s
        const unsigned long long* cb64 = (const unsigned long long*)(cb + 4 * t);
        unsigned long long u0 = __hip_atomic_load(cb64 + 0, __ATOMIC_RELAXED, __HIP_MEMORY_SCOPE_AGENT);
        unsigned long long u1 = __hip_atomic_load(cb64 + 1, __ATOMIC_RELAXED, __HIP_MEMORY_SCOPE_AGENT);
        float4 cv;
        cv.x = __uint_as_float((unsigned)(u0      ));
        cv.y = __uint_as_float((unsigned)(u0 >> 32));
        cv.z = __uint_as_float((unsigned)(u1      ));
        cv.w = __uint_as_float((unsigned)(u1 >> 32));

        // grand total s = sum of column sums (block-redundant reduce)
        float cs = (cv.x + cv.y) + (cv.z + cv.w);
        cs = wave_reduce_sum(cs);
        if (lane == 0) sred[wave] = cs;
        __syncthreads();
        float s = 0.f;
        #pragma unroll
        for (int w = 0; w < 16; ++w) s += sred[w];

        // ---- phase 3: in-register update X <- relu(P1(X))
        const float c0 = INV_N + s * (INV_N * INV_N);
        float4 csub;
        csub.x = cv.x * INV_N; csub.y = cv.y * INV_N;
        csub.z = cv.z * INV_N; csub.w = cv.w * INV_N;
        #pragma unroll
        for (int r = 0; r < RPB; ++r) {
            const float a = c0 - rowsum[r] * INV_N;
            x[r].x = fmaxf(x[r].x + a - csub.x, 0.f);
            x[r].y = fmaxf(x[r].y + a - csub.y, 0.f);
            x[r].z = fmaxf(x[r].z + a - csub.z, 0.f);
            x[r].w = fmaxf(x[r].w + a - csub.w, 0.f);
        }
        __syncthreads();   // protect rowsum/sred reuse next iteration
    }

    // Final store.
    float4* xo = (float4*)Xout;
    #pragma unroll
    for (int r = 0; r < RPB; ++r)
        xo[(size_t)(row0 + r) * NV4 + t] = x[r];
}

extern "C" void kernel_launch(void* const* d_in, const int* in_sizes, int n_in,
                              void* d_out, int out_size, void* d_ws, size_t ws_size,
                              hipStream_t stream)
{
    const float* X0 = (const float*)d_in[0];
    float* X = (float*)d_out;

    // ws layout: arrive counter (one 256 B line) | colbuf[ITERS][NN]
    unsigned* arrive = (unsigned*)d_ws;
    float* colbuf    = (float*)d_ws + 64;

    // Zero barrier counter + all per-iteration column buffers (once; buffers
    // are per-iteration so nothing is ever re-zeroed mid-kernel).
    hipMemsetAsync(d_ws, 0, 256 + (size_t)ITERS * NN * sizeof(float), stream);

    void* args[] = { (void*)&X0, (void*)&X, (void*)&colbuf, (void*)&arrive };
    hipLaunchCooperativeKernel((const void*)persist3,
                               dim3(NBLK), dim3(1024), args, 0, stream);
}

// Round 5
// 521.446 us; speedup vs baseline: 9.9830x; 2.2711x over previous
//
#include <hip/hip_runtime.h>

// Frobenius_71975061946522 — persistent-in-VGPR, fence-free, no RMW storm (R5).
// X (4096x4096 fp32, 64 MB) lives in the unified VGPR/AGPR file across all 20
// iterations: 256 blocks x 1024 threads (1 block/CU); thread t of block b holds
// X[16b+r][4t..4t+3], r=0..15. Row sums are block-local (LDS transpose).
//
// R4 lesson: 1M fp32 atomic-ADDs/iter with fan-in 256 into a 16 KB region
// serialize at the MALL (~50 us/iter). This version exchanges column partials
// with plain agent-scope RELAXED ATOMIC STORES/LOADS (sc1 bypass, coherent at
// the MALL, distinct addresses -> full-rate streaming, zero fences):
//   phase1: store colpart[b][4096] (4 MB/iter)  -> barrier
//   phase2: 64 reducer blocks fold 256->1, store col_out[4096] + s_glob[iter]
//           (single fp32 atomic-add, fan-in 64)  -> barrier
//   phase3: load col_out + s, in-register update X <- relu(P1(X)).

#define NN    4096
#define NV4   1024
#define RPB   16
#define NBLK  256
#define ITERS 20
#define INV_N (1.0f / 4096.0f)

__device__ __forceinline__ float wave_reduce_sum(float v) {
    #pragma unroll
    for (int m = 1; m < 64; m <<= 1) v += __shfl_xor(v, m, 64);
    return v;
}

__device__ __forceinline__ void st_atomic_f32x2(float* p, float a, float b) {
    unsigned long long u = (unsigned long long)__float_as_uint(a)
                         | ((unsigned long long)__float_as_uint(b) << 32);
    __hip_atomic_store((unsigned long long*)p, u, __ATOMIC_RELAXED,
                       __HIP_MEMORY_SCOPE_AGENT);
}
__device__ __forceinline__ float2 ld_atomic_f32x2(const float* p) {
    unsigned long long u = __hip_atomic_load((const unsigned long long*)p,
                                             __ATOMIC_RELAXED, __HIP_MEMORY_SCOPE_AGENT);
    return make_float2(__uint_as_float((unsigned)u),
                       __uint_as_float((unsigned)(u >> 32)));
}
__device__ __forceinline__ float ld_atomic_f32(const float* p) {
    return __hip_atomic_load(p, __ATOMIC_RELAXED, __HIP_MEMORY_SCOPE_AGENT);
}

// Relaxed grid barrier, generation gen (1-based monotonic). Own vmem drained
// first so sc1 stores are at the coherence point before the arrive.
__device__ __forceinline__ void grid_barrier(unsigned* arrive, unsigned gen, int t) {
    asm volatile("s_waitcnt vmcnt(0)" ::: "memory");
    __syncthreads();
    if (t == 0) {
        __hip_atomic_fetch_add(arrive, 1u, __ATOMIC_RELAXED, __HIP_MEMORY_SCOPE_AGENT);
        const unsigned target = (unsigned)NBLK * gen;
        while (__hip_atomic_load(arrive, __ATOMIC_RELAXED, __HIP_MEMORY_SCOPE_AGENT) < target)
            __builtin_amdgcn_s_sleep(1);
    }
    __syncthreads();
}

__global__ __launch_bounds__(1024, 4)
void persist4(const float* __restrict__ X0, float* __restrict__ Xout,
              float* __restrict__ colpart,   // [NBLK][NN]
              float* __restrict__ col_out,   // [NN]
              float* __restrict__ s_glob,    // [ITERS], pre-zeroed
              unsigned* __restrict__ arrive) // monotonic barrier counter
{
    const int t    = threadIdx.x;
    const int wave = t >> 6;
    const int lane = t & 63;
    const int b    = blockIdx.x;
    const int row0 = b * RPB;

    __shared__ float part[1024 * 17];   // row-partial transpose (pad 17)
    __shared__ float rowsum[RPB];
    __shared__ float csum[16][64];      // reducer fold
    __shared__ float sS;

    // Load this thread's 16 float4 of X into registers.
    float4 x[RPB];
    const float4* x0 = (const float4*)X0;
    #pragma unroll
    for (int r = 0; r < RPB; ++r)
        x[r] = x0[(size_t)(row0 + r) * NV4 + t];

    for (int iter = 0; iter < ITERS; ++iter) {
        // ---- phase 1: col partials -> sc1 stores; row sums -> LDS transpose
        float4 cacc = make_float4(0.f, 0.f, 0.f, 0.f);
        #pragma unroll
        for (int r = 0; r < RPB; ++r) {
            cacc.x += x[r].x; cacc.y += x[r].y;
            cacc.z += x[r].z; cacc.w += x[r].w;
            part[t * 17 + r] = (x[r].x + x[r].y) + (x[r].z + x[r].w);
        }
        {
            float* cp = colpart + (size_t)b * NN + 4 * t;
            st_atomic_f32x2(cp,     cacc.x, cacc.y);
            st_atomic_f32x2(cp + 2, cacc.z, cacc.w);
        }
        __syncthreads();
        {   // wave w reduces row w (stride-17 -> conflict-free)
            float v = 0.f;
            #pragma unroll
            for (int k = 0; k < 16; ++k)
                v += part[(lane + 64 * k) * 17 + wave];
            v = wave_reduce_sum(v);
            if (lane == 0) rowsum[wave] = v;
        }
        grid_barrier(arrive, 2 * iter + 1, t);

        // ---- phase 2: 64 reducer blocks fold colpart 256->1
        if (b < 64) {
            const int jl = t & 63;          // column within this block's 64
            const int c  = t >> 6;          // which 16-chunk of 256 sources
            const int j  = (b << 6) + jl;
            float p = 0.f;
            #pragma unroll
            for (int k = 0; k < 16; ++k)
                p += ld_atomic_f32(colpart + (size_t)(c * 16 + k) * NN + j);
            csum[c][jl] = p;
            __syncthreads();
            if (t < 64) {
                float s2 = 0.f;
                #pragma unroll
                for (int c2 = 0; c2 < 16; ++c2) s2 += csum[c2][t];
                __hip_atomic_store(col_out + (b << 6) + t, s2,
                                   __ATOMIC_RELAXED, __HIP_MEMORY_SCOPE_AGENT);
                float sb = wave_reduce_sum(s2);   // t<64 = one full wave
                if (t == 0)
                    __hip_atomic_fetch_add(s_glob + iter, sb,
                                           __ATOMIC_RELAXED, __HIP_MEMORY_SCOPE_AGENT);
            }
        }
        grid_barrier(arrive, 2 * iter + 2, t);

        // ---- phase 3: in-register update X <- relu(P1(X))
        if (t == 0) sS = ld_atomic_f32(s_glob + iter);
        float2 ab = ld_atomic_f32x2(col_out + 4 * t);
        float2 cd = ld_atomic_f32x2(col_out + 4 * t + 2);
        __syncthreads();
        const float s  = sS;
        const float c0 = INV_N + s * (INV_N * INV_N);
        float4 csub;
        csub.x = ab.x * INV_N; csub.y = ab.y * INV_N;
        csub.z = cd.x * INV_N; csub.w = cd.y * INV_N;
        #pragma unroll
        for (int r = 0; r < RPB; ++r) {
            const float a = c0 - rowsum[r] * INV_N;
            x[r].x = fmaxf(x[r].x + a - csub.x, 0.f);
            x[r].y = fmaxf(x[r].y + a - csub.y, 0.f);
            x[r].z = fmaxf(x[r].z + a - csub.z, 0.f);
            x[r].w = fmaxf(x[r].w + a - csub.w, 0.f);
        }
        __syncthreads();   // rowsum/sS protected before next-iter overwrite
    }

    // Final store.
    float4* xo = (float4*)Xout;
    #pragma unroll
    for (int r = 0; r < RPB; ++r)
        xo[(size_t)(row0 + r) * NV4 + t] = x[r];
}

extern "C" void kernel_launch(void* const* d_in, const int* in_sizes, int n_in,
                              void* d_out, int out_size, void* d_ws, size_t ws_size,
                              hipStream_t stream)
{
    const float* X0 = (const float*)d_in[0];
    float* X = (float*)d_out;

    // ws layout (floats): [arrive(1u)+pad .. 64) | s_glob[20] .. | pad to 1024
    //                     | colpart[256*4096] | col_out[4096]
    unsigned* arrive = (unsigned*)d_ws;
    float* s_glob    = (float*)d_ws + 64;
    float* colpart   = (float*)d_ws + 1024;
    float* col_out   = colpart + (size_t)NBLK * NN;

    // Zero control region (arrive + s_glob). colpart/col_out are fully
    // written before read every iteration — no zeroing needed.
    hipMemsetAsync(d_ws, 0, 4096, stream);

    void* args[] = { (void*)&X0, (void*)&X, (void*)&colpart, (void*)&col_out,
                     (void*)&s_glob, (void*)&arrive };
    hipLaunchCooperativeKernel((const void*)persist4,
                               dim3(NBLK), dim3(1024), args, 0, stream);
}

// Round 6
// 339.706 us; speedup vs baseline: 15.3238x; 1.5350x over previous
//
#include <hip/hip_runtime.h>

// Frobenius_71975061946522 — R6: persistent-in-VGPR, two-level fence-free
// barriers, distributed column reduce, non-cooperative launch.
//
// X (4096x4096 fp32, 64 MB) lives in the unified VGPR/AGPR file for all 20
// iterations: 256 blocks x 1024 threads (1 block/CU); thread t of block b
// holds X[16b+r][4t..4t+3], r=0..15. Row sums block-local via LDS transpose.
//
// R5 lesson: each barrier cost ~7 us, dominated by 256-way atomic fan-in on
// ONE counter line (~35 ns/RMW serialized). Fix: two-level arrive — 16 leaf
// counters 256 B apart (fan-in 16, parallel) + root (fan-in 16) -> ~1 us.
// Also: phase2 spread over all 256 blocks (16 cols each), s recomputed
// redundantly per block from col_out (drops the s_glob atomic), and regular
// (non-cooperative) launch to kill the ~105 us wall-vs-kernel gap seen in
// R3-R5. Co-residency is structural: LDS 74 KB + 16 waves -> 1 block/CU,
// grid 256 = CU count (even 2/CU packing keeps all blocks resident).

#define NN    4096
#define NV4   1024
#define RPB   16
#define NBLK  256
#define ITERS 20
#define INV_N (1.0f / 4096.0f)

// barrier region layout (uints): two sets, each: 16 leaves at i*64, root at 1024
#define LEAF_STRIDE 64
#define ROOT_OFF    1024
#define BARSET      2048      // uints per barrier set

__device__ __forceinline__ float wave_reduce_sum(float v) {
    #pragma unroll
    for (int m = 1; m < 64; m <<= 1) v += __shfl_xor(v, m, 64);
    return v;
}

__device__ __forceinline__ void st_atomic_f32x2(float* p, float a, float b) {
    unsigned long long u = (unsigned long long)__float_as_uint(a)
                         | ((unsigned long long)__float_as_uint(b) << 32);
    __hip_atomic_store((unsigned long long*)p, u, __ATOMIC_RELAXED,
                       __HIP_MEMORY_SCOPE_AGENT);
}
__device__ __forceinline__ float2 ld_atomic_f32x2(const float* p) {
    unsigned long long u = __hip_atomic_load((const unsigned long long*)p,
                                             __ATOMIC_RELAXED, __HIP_MEMORY_SCOPE_AGENT);
    return make_float2(__uint_as_float((unsigned)u),
                       __uint_as_float((unsigned)(u >> 32)));
}
__device__ __forceinline__ float ld_atomic_f32(const float* p) {
    return __hip_atomic_load(p, __ATOMIC_RELAXED, __HIP_MEMORY_SCOPE_AGENT);
}
__device__ __forceinline__ void st_atomic_f32(float* p, float v) {
    __hip_atomic_store(p, v, __ATOMIC_RELAXED, __HIP_MEMORY_SCOPE_AGENT);
}

// Two-level relaxed grid barrier, generation gen (1-based monotonic).
// Own vmem drained first so this block's sc-atomic stores are at the
// coherence point before the arrive. Zero fences anywhere.
__device__ __forceinline__ void grid_barrier(unsigned* base, int b, unsigned gen, int t) {
    asm volatile("s_waitcnt vmcnt(0)" ::: "memory");
    __syncthreads();
    if (t == 0) {
        unsigned* leaf = base + (b & 15) * LEAF_STRIDE;
        unsigned* root = base + ROOT_OFF;
        unsigned old = __hip_atomic_fetch_add(leaf, 1u, __ATOMIC_RELAXED,
                                              __HIP_MEMORY_SCOPE_AGENT);
        if (old == gen * 16u - 1u)     // 16th arrival at this leaf this gen
            __hip_atomic_fetch_add(root, 1u, __ATOMIC_RELAXED,
                                   __HIP_MEMORY_SCOPE_AGENT);
        while (__hip_atomic_load(root, __ATOMIC_RELAXED,
                                 __HIP_MEMORY_SCOPE_AGENT) < gen * 16u)
            __builtin_amdgcn_s_sleep(1);
    }
    __syncthreads();
}

__global__ __launch_bounds__(1024, 4)
void persist5(const float* __restrict__ X0, float* __restrict__ Xout,
              float* __restrict__ colpart,   // [NBLK][NN]
              float* __restrict__ col_out,   // [NN]
              unsigned* __restrict__ bar)    // two barrier sets
{
    const int t    = threadIdx.x;
    const int wave = t >> 6;
    const int lane = t & 63;
    const int b    = blockIdx.x;
    const int row0 = b * RPB;

    __shared__ float part[1024 * 17];   // row-partial transpose (pad 17)
    __shared__ float csum[64 * 17];     // phase2 fold (pad 17)
    __shared__ float rowsum[RPB];
    __shared__ float sred[16];

    // Load this thread's 16 float4 of X into registers.
    float4 x[RPB];
    const float4* x0 = (const float4*)X0;
    #pragma unroll
    for (int r = 0; r < RPB; ++r)
        x[r] = x0[(size_t)(row0 + r) * NV4 + t];

    for (int iter = 0; iter < ITERS; ++iter) {
        const unsigned gen = (unsigned)iter + 1u;

        // ---- phase 1: col partials -> global stores; row sums -> LDS transpose
        float4 cacc = make_float4(0.f, 0.f, 0.f, 0.f);
        #pragma unroll
        for (int r = 0; r < RPB; ++r) {
            cacc.x += x[r].x; cacc.y += x[r].y;
            cacc.z += x[r].z; cacc.w += x[r].w;
            part[t * 17 + r] = (x[r].x + x[r].y) + (x[r].z + x[r].w);
        }
        {
            float* cp = colpart + (size_t)b * NN + 4 * t;
            st_atomic_f32x2(cp,     cacc.x, cacc.y);
            st_atomic_f32x2(cp + 2, cacc.z, cacc.w);
        }
        __syncthreads();   // part complete; also: prior-iter rowsum reads done
        {   // wave w reduces row w (stride-17 -> <=2-way alias, free)
            float v = 0.f;
            #pragma unroll
            for (int k = 0; k < 16; ++k)
                v += part[(lane + 64 * k) * 17 + wave];
            v = wave_reduce_sum(v);
            if (lane == 0) rowsum[wave] = v;
        }
        grid_barrier(bar, b, gen, t);              // barrier A

        // ---- phase 2: block b reduces columns [16b, 16b+16)
        {
            const int jl = t & 15;                 // column within the 16
            const int c  = t >> 4;                 // chunk 0..63 (4 rows each)
            const float* cp = colpart + (size_t)(4 * c) * NN + (b << 4) + jl;
            float p = ld_atomic_f32(cp)
                    + ld_atomic_f32(cp + NN)
                    + ld_atomic_f32(cp + 2 * NN)
                    + ld_atomic_f32(cp + 3 * NN);
            csum[c * 17 + jl] = p;
            __syncthreads();
            // wave w folds column w: lane l reads csum[l][w] (17-pad: free)
            float v = csum[lane * 17 + wave];
            v = wave_reduce_sum(v);
            if (lane == 0) st_atomic_f32(col_out + (b << 4) + wave, v);
        }
        grid_barrier(bar + BARSET, b, gen, t);     // barrier B

        // ---- phase 3: load col sums, redundant total, in-register update
        float2 ab = ld_atomic_f32x2(col_out + 4 * t);
        float2 cd = ld_atomic_f32x2(col_out + 4 * t + 2);
        {   // redundant grand total (identical sequence in every block)
            float cs = (ab.x + ab.y) + (cd.x + cd.y);
            cs = wave_reduce_sum(cs);
            if (lane == 0) sred[wave] = cs;
        }
        __syncthreads();
        float s = 0.f;
        #pragma unroll
        for (int w = 0; w < 16; ++w) s += sred[w];

        const float c0 = INV_N + s * (INV_N * INV_N);
        float4 csub;
        csub.x = ab.x * INV_N; csub.y = ab.y * INV_N;
        csub.z = cd.x * INV_N; csub.w = cd.y * INV_N;
        #pragma unroll
        for (int r = 0; r < RPB; ++r) {
            const float a = c0 - rowsum[r] * INV_N;
            x[r].x = fmaxf(x[r].x + a - csub.x, 0.f);
            x[r].y = fmaxf(x[r].y + a - csub.y, 0.f);
            x[r].z = fmaxf(x[r].z + a - csub.z, 0.f);
            x[r].w = fmaxf(x[r].w + a - csub.w, 0.f);
        }
        // next iteration's leading __syncthreads protects rowsum/sred reuse
    }

    // Final store.
    float4* xo = (float4*)Xout;
    #pragma unroll
    for (int r = 0; r < RPB; ++r)
        xo[(size_t)(row0 + r) * NV4 + t] = x[r];
}

extern "C" void kernel_launch(void* const* d_in, const int* in_sizes, int n_in,
                              void* d_out, int out_size, void* d_ws, size_t ws_size,
                              hipStream_t stream)
{
    const float* X0 = (const float*)d_in[0];
    float* X = (float*)d_out;

    // ws layout: barrier region (2 sets x 2048 uints = 16 KB) |
    //            colpart[256*4096] | col_out[4096]
    unsigned* bar  = (unsigned*)d_ws;
    float* colpart = (float*)d_ws + 2 * BARSET;
    float* col_out = colpart + (size_t)NBLK * NN;

    hipMemsetAsync(d_ws, 0, 2 * BARSET * sizeof(unsigned), stream);

    // Regular launch: no CG API used; all 256 blocks fit simultaneously
    // (1 block/CU). Cuts the ~105 us cooperative-launch overhead seen R3-R5.
    persist5<<<dim3(NBLK), dim3(1024), 0, stream>>>(X0, X, colpart, col_out, bar);
}